// Round 2
// baseline (127.003 us; speedup 1.0000x reference)
//
#include <hip/hip_runtime.h>

// Problem constants
// N=2, L=1024, C=256, H=64, E=16, CL=64, LAYERS=4
// LOUT = L - CL = 960
// Projections: q,k: (N,L,H*E)=2048x1024 ; v: (N,L,H)=2048x64
// Stored transposed: qT/kT: [n][h][l][e], vT: [n][h][l]

#define NL_TOT 2048   // N*L rows of X

// ---------------------------------------------------------------------------
// Kernel 1: fused QKV projection GEMM. C[m,o] = dot(X[m,:], W_sel[o_local,:]) + b.
// m in [0,2048): n = m>>10, l = m&1023.  o in [0,2112): [0,1024)=Q, [1024,2048)=K, [2048,2112)=V.
// 64x64 tiles, 4x4 micro-tile per thread, K-tile = 32.
// ---------------------------------------------------------------------------
__global__ __launch_bounds__(256) void qkv_gemm(
    const float* __restrict__ X,
    const float* __restrict__ Wq, const float* __restrict__ bq,
    const float* __restrict__ Wk, const float* __restrict__ bk,
    const float* __restrict__ Wv, const float* __restrict__ bv,
    float* __restrict__ qT, float* __restrict__ kT, float* __restrict__ vT)
{
    // Xs/Ws layout: [k][m] with row stride 68 floats (272B, 16B-aligned, bank-spread)
    __shared__ float Xs[32 * 68];
    __shared__ float Ws[32 * 68];

    const int tid = threadIdx.x;
    const int bm = blockIdx.x;    // 0..31, 64 rows of X each
    const int bo = blockIdx.y;    // 0..32, 64 output cols each
    const int o0 = bo * 64;

    const float* W; const float* bias; int wrow0; int mode;
    if (o0 < 1024)      { W = Wq; bias = bq; wrow0 = o0;        mode = 0; }
    else if (o0 < 2048) { W = Wk; bias = bk; wrow0 = o0 - 1024; mode = 1; }
    else                { W = Wv; bias = bv; wrow0 = 0;         mode = 2; }

    const int lrow = tid >> 3;          // 0..31
    const int lcol = (tid & 7) * 4;     // 0,4,...,28

    const int ty = tid >> 4;            // 0..15 -> m micro-row
    const int tx = tid & 15;            // 0..15 -> o micro-col

    float acc[4][4];
    #pragma unroll
    for (int i = 0; i < 4; ++i)
        #pragma unroll
        for (int j = 0; j < 4; ++j) acc[i][j] = 0.f;

    for (int k0 = 0; k0 < 256; k0 += 32) {
        #pragma unroll
        for (int p = 0; p < 2; ++p) {
            const int row = lrow + p * 32;  // 0..63
            float4 xv = *reinterpret_cast<const float4*>(&X[(bm * 64 + row) * 256 + k0 + lcol]);
            Xs[(lcol + 0) * 68 + row] = xv.x;
            Xs[(lcol + 1) * 68 + row] = xv.y;
            Xs[(lcol + 2) * 68 + row] = xv.z;
            Xs[(lcol + 3) * 68 + row] = xv.w;
            float4 wv = *reinterpret_cast<const float4*>(&W[(wrow0 + row) * 256 + k0 + lcol]);
            Ws[(lcol + 0) * 68 + row] = wv.x;
            Ws[(lcol + 1) * 68 + row] = wv.y;
            Ws[(lcol + 2) * 68 + row] = wv.z;
            Ws[(lcol + 3) * 68 + row] = wv.w;
        }
        __syncthreads();
        #pragma unroll
        for (int kk = 0; kk < 32; ++kk) {
            float4 av = *reinterpret_cast<const float4*>(&Xs[kk * 68 + ty * 4]);
            float4 bv4 = *reinterpret_cast<const float4*>(&Ws[kk * 68 + tx * 4]);
            acc[0][0] += av.x * bv4.x; acc[0][1] += av.x * bv4.y; acc[0][2] += av.x * bv4.z; acc[0][3] += av.x * bv4.w;
            acc[1][0] += av.y * bv4.x; acc[1][1] += av.y * bv4.y; acc[1][2] += av.y * bv4.z; acc[1][3] += av.y * bv4.w;
            acc[2][0] += av.z * bv4.x; acc[2][1] += av.z * bv4.y; acc[2][2] += av.z * bv4.z; acc[2][3] += av.z * bv4.w;
            acc[3][0] += av.w * bv4.x; acc[3][1] += av.w * bv4.y; acc[3][2] += av.w * bv4.z; acc[3][3] += av.w * bv4.w;
        }
        __syncthreads();
    }

    // Epilogue: bias + transposed scatter
    #pragma unroll
    for (int j = 0; j < 4; ++j) {
        const int ol = wrow0 + tx * 4 + j;     // local row within selected W
        const float bj = bias[ol];
        #pragma unroll
        for (int i = 0; i < 4; ++i) {
            const int m = bm * 64 + ty * 4 + i;
            const int n = m >> 10;
            const int l = m & 1023;
            const float val = acc[i][j] + bj;
            if (mode == 2) {
                vT[(n * 64 + ol) * 1024 + l] = val;
            } else {
                const int h = ol >> 4, e = ol & 15;
                float* T = (mode == 0) ? qT : kT;
                T[((n * 64 + h) * 1024 + l) * 16 + e] = val;
            }
        }
    }
}

// ---------------------------------------------------------------------------
// Kernel 2: sliding-window attention + PE + softmax + weighted V + ReLU.
// Block = 1 wave (64 lanes). Block handles (n, h, 32 output positions).
// Lane = window position d. Output position l: q row l+32, k/v rows l..l+63.
// ---------------------------------------------------------------------------
__global__ __launch_bounds__(64) void attn_kernel(
    const float* __restrict__ qT, const float* __restrict__ kT,
    const float* __restrict__ vT, const float* __restrict__ PE,
    float* __restrict__ att)
{
    __shared__ float k_lds[95 * 17];   // rows l0..l0+94, 16 floats each, pad 17
    __shared__ float q_lds[32 * 16];   // q rows l0+32 .. l0+63+32
    __shared__ float v_lds[96];

    const int lane = threadIdx.x;
    const int lt = blockIdx.x;     // 0..29
    const int h  = blockIdx.y;     // 0..63
    const int n  = blockIdx.z;     // 0..1
    const int l0 = lt * 32;

    const float* kbase = kT + ((n * 64 + h) * 1024 + l0) * 16;
    for (int idx = lane; idx < 95 * 16; idx += 64)
        k_lds[(idx >> 4) * 17 + (idx & 15)] = kbase[idx];

    const float* qbase = qT + ((n * 64 + h) * 1024 + l0 + 32) * 16;
    for (int idx = lane; idx < 32 * 16; idx += 64)
        q_lds[idx] = qbase[idx];

    const float* vbase = vT + (n * 64 + h) * 1024 + l0;
    for (int idx = lane; idx < 95; idx += 64)
        v_lds[idx] = vbase[idx];

    float pe[16];
    #pragma unroll
    for (int e = 0; e < 16; ++e)
        pe[e] = PE[(lane * 64 + h) * 16 + e];

    __syncthreads();

    for (int i = 0; i < 32; ++i) {
        // score for window slot d = lane
        float s = 0.f;
        const float* kr = &k_lds[(i + lane) * 17];
        #pragma unroll
        for (int e = 0; e < 16; ++e)
            s += q_lds[i * 16 + e] * (kr[e] + pe[e]);

        // softmax over 64 lanes
        float mx = s;
        #pragma unroll
        for (int off = 32; off >= 1; off >>= 1)
            mx = fmaxf(mx, __shfl_xor(mx, off));
        const float p = __expf(s - mx);
        const float vv = v_lds[i + lane];
        float ps = p;
        float pv = p * vv;
        #pragma unroll
        for (int off = 32; off >= 1; off >>= 1) {
            ps += __shfl_xor(ps, off);
            pv += __shfl_xor(pv, off);
        }
        if (lane == 0)
            att[(n * 960 + l0 + i) * 64 + h] = fmaxf(pv / ps, 0.f);
    }
}

// ---------------------------------------------------------------------------
// Kernel 3: 4x FC(64->64, ReLU) + final (3x64) head.
// Block = 256 threads (4 waves), handles 16 rows of the 1920 (n,l) rows.
// Thread = (wave wv = row phase, lane o = output unit).
// ---------------------------------------------------------------------------
__global__ __launch_bounds__(256) void fc_kernel(
    const float* __restrict__ att,
    const float* __restrict__ fc_w, const float* __restrict__ fc_b,
    const float* __restrict__ Wout, const float* __restrict__ bout,
    float* __restrict__ out)
{
    __shared__ float w_lds[64 * 65];     // one layer's weights, pad 65
    __shared__ float wo_lds[3 * 64];
    __shared__ float bufA[16 * 65];
    __shared__ float bufB[16 * 65];

    const int tid = threadIdx.x;
    const int o  = tid & 63;
    const int wv = tid >> 6;
    const int R0 = blockIdx.x * 16;

    for (int idx = tid; idx < 192; idx += 256) wo_lds[idx] = Wout[idx];
    for (int idx = tid; idx < 16 * 64; idx += 256) {
        const int r = idx >> 6, hh = idx & 63;
        bufA[r * 65 + hh] = att[(R0 + r) * 64 + hh];
    }

    float* cur = bufA;
    float* nxt = bufB;

    for (int layer = 0; layer < 4; ++layer) {
        __syncthreads();   // cur ready (and w_lds free to overwrite)
        for (int idx = tid; idx < 4096; idx += 256) {
            const int oo = idx >> 6, hh = idx & 63;
            // NOTE: parenthesization matters — was `layer*4096 + idx & 4095`
            // which binds as `(layer*4096+idx) & 4095` == idx (layer-0 weights
            // for every layer). Fixed:
            w_lds[oo * 65 + hh] = fc_w[layer * 4096 + idx];
        }
        __syncthreads();
        const float bias = fc_b[layer * 64 + o];
        for (int r = wv; r < 16; r += 4) {
            float acc = bias;
            #pragma unroll
            for (int hh = 0; hh < 64; ++hh)
                acc += cur[r * 65 + hh] * w_lds[o * 65 + hh];
            nxt[r * 65 + o] = fmaxf(acc, 0.f);
        }
        float* t = cur; cur = nxt; nxt = t;
    }
    __syncthreads();

    // final head: 3 outputs per row
    if (o < 3) {
        const float bo_ = bout[o];
        for (int r = wv; r < 16; r += 4) {
            float acc = bo_;
            #pragma unroll
            for (int hh = 0; hh < 64; ++hh)
                acc += cur[r * 65 + hh] * wo_lds[o * 64 + hh];
            out[(R0 + r) * 3 + o] = acc;
        }
    }
}

// ---------------------------------------------------------------------------
extern "C" void kernel_launch(void* const* d_in, const int* in_sizes, int n_in,
                              void* d_out, int out_size, void* d_ws, size_t ws_size,
                              hipStream_t stream) {
    const float* x    = (const float*)d_in[0];
    const float* Wq   = (const float*)d_in[1];
    const float* bq   = (const float*)d_in[2];
    const float* Wk   = (const float*)d_in[3];
    const float* bk   = (const float*)d_in[4];
    const float* Wv   = (const float*)d_in[5];
    const float* bv   = (const float*)d_in[6];
    const float* PE   = (const float*)d_in[7];
    const float* fc_w = (const float*)d_in[8];
    const float* fc_b = (const float*)d_in[9];
    const float* Wout = (const float*)d_in[10];
    const float* bout = (const float*)d_in[11];
    float* out = (float*)d_out;

    float* ws = (float*)d_ws;
    float* qT  = ws;                       // 2*64*1024*16 = 2,097,152 floats
    float* kT  = qT + 2 * 64 * 1024 * 16;  // 2,097,152
    float* vT  = kT + 2 * 64 * 1024 * 16;  // 2*64*1024 = 131,072
    float* att = vT + 2 * 64 * 1024;       // 2*960*64  = 122,880

    qkv_gemm<<<dim3(32, 33), 256, 0, stream>>>(x, Wq, bq, Wk, bk, Wv, bv, qT, kT, vT);
    attn_kernel<<<dim3(30, 64, 2), 64, 0, stream>>>(qT, kT, vT, PE, att);
    fc_kernel<<<dim3(120), 256, 0, stream>>>(att, fc_w, fc_b, Wout, bout, out);
}

// Round 3
// 103.902 us; speedup vs baseline: 1.2223x; 1.2223x over previous
//
#include <hip/hip_runtime.h>

// N=2, L=1024, C=256, H=64, E=16, CL=64, LOUT=960
// qT/kT: [n][h][l][e] fp32 ; vT: [n][h][l] fp32

typedef __attribute__((ext_vector_type(8))) __bf16 bf16x8;
typedef __attribute__((ext_vector_type(8))) short short8;
typedef __attribute__((ext_vector_type(4))) float f32x4;

__device__ inline unsigned short bf16_rne(float x) {
    unsigned u = __builtin_bit_cast(unsigned, x);
    unsigned r = u + 0x7fffu + ((u >> 16) & 1u);
    return (unsigned short)(r >> 16);
}
__device__ inline float bf16_f(unsigned short h) {
    return __builtin_bit_cast(float, (unsigned)h << 16);
}

// ---------------------------------------------------------------------------
// Kernel 0: split X and W=[Wq;Wk;Wv] into bf16 hi/lo planes.
// X: 2048x256 -> XhG/XlG. W: 2112x256 -> WhG/WlG (rows 0-1023 Wq, 1024-2047 Wk,
// 2048-2111 Wv).
// ---------------------------------------------------------------------------
__global__ __launch_bounds__(256) void convert_split(
    const float* __restrict__ X,
    const float* __restrict__ Wq, const float* __restrict__ Wk, const float* __restrict__ Wv,
    unsigned short* __restrict__ XhG, unsigned short* __restrict__ XlG,
    unsigned short* __restrict__ WhG, unsigned short* __restrict__ WlG)
{
    const int g = blockIdx.x * 256 + threadIdx.x;   // float4 group
    const int NX = 131072;                          // 2048*256/4
    const int NW = 135168;                          // 2112*256/4
    if (g >= NX + NW) return;

    float4 v;
    unsigned short *dh, *dl;
    int off;
    if (g < NX) {
        off = g * 4;
        v = *reinterpret_cast<const float4*>(&X[off]);
        dh = XhG; dl = XlG;
    } else {
        off = (g - NX) * 4;
        const int row = off >> 8, col = off & 255;
        const float* s;
        if (row < 1024)      s = &Wq[row * 256 + col];
        else if (row < 2048) s = &Wk[(row - 1024) * 256 + col];
        else                 s = &Wv[(row - 2048) * 256 + col];
        v = *reinterpret_cast<const float4*>(s);
        dh = WhG; dl = WlG;
    }
    unsigned short h0 = bf16_rne(v.x), h1 = bf16_rne(v.y), h2 = bf16_rne(v.z), h3 = bf16_rne(v.w);
    unsigned short l0 = bf16_rne(v.x - bf16_f(h0));
    unsigned short l1 = bf16_rne(v.y - bf16_f(h1));
    unsigned short l2 = bf16_rne(v.z - bf16_f(h2));
    unsigned short l3 = bf16_rne(v.w - bf16_f(h3));
    ushort4 hv = make_ushort4(h0, h1, h2, h3);
    ushort4 lv = make_ushort4(l0, l1, l2, l3);
    *reinterpret_cast<ushort4*>(&dh[off]) = hv;
    *reinterpret_cast<ushort4*>(&dl[off]) = lv;
}

// ---------------------------------------------------------------------------
// Kernel 1: QKV projection via MFMA, bf16 split-3 (XhWh + XhWl + XlWh).
// Block 256 thr (4 waves, 2x2), tile 128x128, k-step 64.
// LDS: 3 tiles of 128x(64+8) bf16 = 55296 B (<64K static limit).
//   phase A: {Xh,Wh,Wl} -> acc += Xh*Wh + Xh*Wl
//   phase B: restage Xl over C -> acc += Xl*Wh
// Grid (16, 17): y<8 Q, y<16 K, y=16 V (64 valid cols).
// ---------------------------------------------------------------------------
#define LDA 72   // padded row stride in bf16 (144 B, 16B-aligned, conflict-free)

__global__ __launch_bounds__(256) void qkv_mfma(
    const unsigned short* __restrict__ XhG, const unsigned short* __restrict__ XlG,
    const unsigned short* __restrict__ WhG, const unsigned short* __restrict__ WlG,
    const float* __restrict__ bq, const float* __restrict__ bk, const float* __restrict__ bv,
    float* __restrict__ qT, float* __restrict__ kT, float* __restrict__ vT)
{
    __shared__ unsigned short A_lds[128 * LDA];  // Xh
    __shared__ unsigned short B_lds[128 * LDA];  // Wh
    __shared__ unsigned short C_lds[128 * LDA];  // Wl, then Xl

    const int tid = threadIdx.x;
    const int lane = tid & 63;
    const int wid = tid >> 6;
    const int wm = wid >> 1, wn = wid & 1;
    const int m0 = blockIdx.x * 128;
    const int o0 = blockIdx.y * 128;

    f32x4 acc[4][4];
    #pragma unroll
    for (int i = 0; i < 4; ++i)
        #pragma unroll
        for (int j = 0; j < 4; ++j)
            acc[i][j] = f32x4{0.f, 0.f, 0.f, 0.f};

    const short8 zero8 = {0, 0, 0, 0, 0, 0, 0, 0};

    for (int k0 = 0; k0 < 256; k0 += 64) {
        // ---- phase A stage: Xh, Wh, Wl
        __syncthreads();
        #pragma unroll
        for (int i = tid; i < 1024; i += 256) {
            const int row = i >> 3, lc = (i & 7) * 8;
            *reinterpret_cast<short8*>(&A_lds[row * LDA + lc]) =
                *reinterpret_cast<const short8*>(&XhG[(m0 + row) * 256 + k0 + lc]);
            const int orow = o0 + row;
            short8 wh = zero8, wl = zero8;
            if (orow < 2112) {
                wh = *reinterpret_cast<const short8*>(&WhG[orow * 256 + k0 + lc]);
                wl = *reinterpret_cast<const short8*>(&WlG[orow * 256 + k0 + lc]);
            }
            *reinterpret_cast<short8*>(&B_lds[row * LDA + lc]) = wh;
            *reinterpret_cast<short8*>(&C_lds[row * LDA + lc]) = wl;
        }
        __syncthreads();
        #pragma unroll
        for (int kk = 0; kk < 64; kk += 32) {
            const int colb = kk + ((lane >> 4) << 3);
            bf16x8 aH[4], bH[4], bL[4];
            #pragma unroll
            for (int t = 0; t < 4; ++t) {
                const int ar = wm * 64 + t * 16 + (lane & 15);
                const int br = wn * 64 + t * 16 + (lane & 15);
                aH[t] = __builtin_bit_cast(bf16x8, *reinterpret_cast<const short8*>(&A_lds[ar * LDA + colb]));
                bH[t] = __builtin_bit_cast(bf16x8, *reinterpret_cast<const short8*>(&B_lds[br * LDA + colb]));
                bL[t] = __builtin_bit_cast(bf16x8, *reinterpret_cast<const short8*>(&C_lds[br * LDA + colb]));
            }
            #pragma unroll
            for (int mt = 0; mt < 4; ++mt)
                #pragma unroll
                for (int ot = 0; ot < 4; ++ot) {
                    acc[mt][ot] = __builtin_amdgcn_mfma_f32_16x16x32_bf16(aH[mt], bH[ot], acc[mt][ot], 0, 0, 0);
                    acc[mt][ot] = __builtin_amdgcn_mfma_f32_16x16x32_bf16(aH[mt], bL[ot], acc[mt][ot], 0, 0, 0);
                }
        }
        // ---- phase B stage: Xl over C
        __syncthreads();
        #pragma unroll
        for (int i = tid; i < 1024; i += 256) {
            const int row = i >> 3, lc = (i & 7) * 8;
            *reinterpret_cast<short8*>(&C_lds[row * LDA + lc]) =
                *reinterpret_cast<const short8*>(&XlG[(m0 + row) * 256 + k0 + lc]);
        }
        __syncthreads();
        #pragma unroll
        for (int kk = 0; kk < 64; kk += 32) {
            const int colb = kk + ((lane >> 4) << 3);
            bf16x8 aL[4], bH[4];
            #pragma unroll
            for (int t = 0; t < 4; ++t) {
                const int ar = wm * 64 + t * 16 + (lane & 15);
                const int br = wn * 64 + t * 16 + (lane & 15);
                aL[t] = __builtin_bit_cast(bf16x8, *reinterpret_cast<const short8*>(&C_lds[ar * LDA + colb]));
                bH[t] = __builtin_bit_cast(bf16x8, *reinterpret_cast<const short8*>(&B_lds[br * LDA + colb]));
            }
            #pragma unroll
            for (int mt = 0; mt < 4; ++mt)
                #pragma unroll
                for (int ot = 0; ot < 4; ++ot)
                    acc[mt][ot] = __builtin_amdgcn_mfma_f32_16x16x32_bf16(aL[mt], bH[ot], acc[mt][ot], 0, 0, 0);
        }
    }

    // ---- epilogue: bias + transposed scatter
    // D frag: col = lane&15 (o dim), row = (lane>>4)*4 + reg (m dim)
    const int drow = (lane >> 4) * 4;
    const int dcol = lane & 15;
    const int mode = (o0 < 1024) ? 0 : (o0 < 2048 ? 1 : 2);

    if (mode < 2) {
        float* __restrict__ T = mode ? kT : qT;
        const float* __restrict__ bias = mode ? bk : bq;
        const int ob = mode * 1024;
        #pragma unroll
        for (int ot = 0; ot < 4; ++ot) {
            const int o = o0 + wn * 64 + ot * 16 + dcol;
            const int h = (o >> 4) & 63;
            const int e = o & 15;
            const float bval = bias[o - ob];
            #pragma unroll
            for (int mt = 0; mt < 4; ++mt)
                #pragma unroll
                for (int r = 0; r < 4; ++r) {
                    const int m = m0 + wm * 64 + mt * 16 + drow + r;
                    const int n = m >> 10, l = m & 1023;
                    T[((n * 64 + h) * 1024 + l) * 16 + e] = acc[mt][ot][r] + bval;
                }
        }
    } else if (wn == 0) {   // V: only cols 2048..2111 valid (wn==0 half)
        #pragma unroll
        for (int ot = 0; ot < 4; ++ot) {
            const int hV = ot * 16 + dcol;   // 0..63
            const float bval = bv[hV];
            #pragma unroll
            for (int mt = 0; mt < 4; ++mt)
                #pragma unroll
                for (int r = 0; r < 4; ++r) {
                    const int m = m0 + wm * 64 + mt * 16 + drow + r;
                    const int n = m >> 10, l = m & 1023;
                    vT[(n * 64 + hV) * 1024 + l] = acc[mt][ot][r] + bval;
                }
        }
    }
}

// ---------------------------------------------------------------------------
// Kernel 2: sliding-window attention + PE + softmax + weighted V + ReLU.
// Block = 1 wave. Lane = window slot d. 32 output positions per block.
// ---------------------------------------------------------------------------
__global__ __launch_bounds__(64) void attn_kernel(
    const float* __restrict__ qT, const float* __restrict__ kT,
    const float* __restrict__ vT, const float* __restrict__ PE,
    float* __restrict__ att)
{
    __shared__ float k_lds[95 * 17];
    __shared__ float q_lds[32 * 16];
    __shared__ float v_lds[96];

    const int lane = threadIdx.x;
    const int lt = blockIdx.x;
    const int h  = blockIdx.y;
    const int n  = blockIdx.z;
    const int l0 = lt * 32;

    const float* kbase = kT + ((n * 64 + h) * 1024 + l0) * 16;
    for (int idx = lane; idx < 95 * 16; idx += 64)
        k_lds[(idx >> 4) * 17 + (idx & 15)] = kbase[idx];

    const float* qbase = qT + ((n * 64 + h) * 1024 + l0 + 32) * 16;
    for (int idx = lane; idx < 32 * 16; idx += 64)
        q_lds[idx] = qbase[idx];

    const float* vbase = vT + (n * 64 + h) * 1024 + l0;
    for (int idx = lane; idx < 95; idx += 64)
        v_lds[idx] = vbase[idx];

    float pe[16];
    #pragma unroll
    for (int e = 0; e < 16; ++e)
        pe[e] = PE[(lane * 64 + h) * 16 + e];

    __syncthreads();

    for (int i = 0; i < 32; ++i) {
        float s = 0.f;
        const float* kr = &k_lds[(i + lane) * 17];
        #pragma unroll
        for (int e = 0; e < 16; ++e)
            s += q_lds[i * 16 + e] * (kr[e] + pe[e]);

        float mx = s;
        #pragma unroll
        for (int off = 32; off >= 1; off >>= 1)
            mx = fmaxf(mx, __shfl_xor(mx, off));
        const float p = __expf(s - mx);
        const float vv = v_lds[i + lane];
        float ps = p;
        float pv = p * vv;
        #pragma unroll
        for (int off = 32; off >= 1; off >>= 1) {
            ps += __shfl_xor(ps, off);
            pv += __shfl_xor(pv, off);
        }
        if (lane == 0)
            att[(n * 960 + l0 + i) * 64 + h] = fmaxf(pv / ps, 0.f);
    }
}

// ---------------------------------------------------------------------------
// Kernel 3: 4x FC(64->64, ReLU) + final (3x64) head. float4 LDS reads, pad 68.
// ---------------------------------------------------------------------------
__global__ __launch_bounds__(256) void fc_kernel(
    const float* __restrict__ att,
    const float* __restrict__ fc_w, const float* __restrict__ fc_b,
    const float* __restrict__ Wout, const float* __restrict__ bout,
    float* __restrict__ out)
{
    __shared__ float w_lds[64 * 68];
    __shared__ float wo_lds[3 * 64];
    __shared__ float bufA[16 * 68];
    __shared__ float bufB[16 * 68];

    const int tid = threadIdx.x;
    const int o  = tid & 63;
    const int wv = tid >> 6;
    const int R0 = blockIdx.x * 16;

    for (int idx = tid; idx < 192; idx += 256) wo_lds[idx] = Wout[idx];
    for (int idx = tid; idx < 16 * 64; idx += 256) {
        const int r = idx >> 6, hh = idx & 63;
        bufA[r * 68 + hh] = att[(R0 + r) * 64 + hh];
    }

    float* cur = bufA;
    float* nxt = bufB;

    for (int layer = 0; layer < 4; ++layer) {
        __syncthreads();
        for (int idx = tid; idx < 4096; idx += 256) {
            const int oo = idx >> 6, hh = idx & 63;
            w_lds[oo * 68 + hh] = fc_w[layer * 4096 + idx];
        }
        __syncthreads();
        const float bias = fc_b[layer * 64 + o];
        const float4* wr = reinterpret_cast<const float4*>(&w_lds[o * 68]);
        for (int r = wv; r < 16; r += 4) {
            const float4* cr = reinterpret_cast<const float4*>(&cur[r * 68]);
            float acc = bias;
            #pragma unroll
            for (int q = 0; q < 16; ++q) {
                const float4 c = cr[q], w = wr[q];
                acc += c.x * w.x + c.y * w.y + c.z * w.z + c.w * w.w;
            }
            nxt[r * 68 + o] = fmaxf(acc, 0.f);
        }
        float* t = cur; cur = nxt; nxt = t;
    }
    __syncthreads();

    if (o < 3) {
        const float bo_ = bout[o];
        for (int r = wv; r < 16; r += 4) {
            float acc = bo_;
            #pragma unroll
            for (int hh = 0; hh < 64; ++hh)
                acc += cur[r * 68 + hh] * wo_lds[o * 64 + hh];
            out[(R0 + r) * 3 + o] = acc;
        }
    }
}

// ---------------------------------------------------------------------------
extern "C" void kernel_launch(void* const* d_in, const int* in_sizes, int n_in,
                              void* d_out, int out_size, void* d_ws, size_t ws_size,
                              hipStream_t stream) {
    const float* x    = (const float*)d_in[0];
    const float* Wq   = (const float*)d_in[1];
    const float* bq   = (const float*)d_in[2];
    const float* Wk   = (const float*)d_in[3];
    const float* bk   = (const float*)d_in[4];
    const float* Wv   = (const float*)d_in[5];
    const float* bv   = (const float*)d_in[6];
    const float* PE   = (const float*)d_in[7];
    const float* fc_w = (const float*)d_in[8];
    const float* fc_b = (const float*)d_in[9];
    const float* Wout = (const float*)d_in[10];
    const float* bout = (const float*)d_in[11];
    float* out = (float*)d_out;

    float* ws = (float*)d_ws;
    float* qT  = ws;                       // 2,097,152 f
    float* kT  = qT + 2097152;             // 2,097,152 f
    float* vT  = kT + 2097152;             // 131,072 f
    float* att = vT + 131072;              // 122,880 f
    unsigned short* XhG = (unsigned short*)(att + 122880);  // 524,288 us
    unsigned short* XlG = XhG + 524288;                     // 524,288 us
    unsigned short* WhG = XlG + 524288;                     // 540,672 us
    unsigned short* WlG = WhG + 540672;                     // 540,672 us
    // total ws: ~22.1 MB

    convert_split<<<1040, 256, 0, stream>>>(x, Wq, Wk, Wv, XhG, XlG, WhG, WlG);
    qkv_mfma<<<dim3(16, 17), 256, 0, stream>>>(XhG, XlG, WhG, WlG, bq, bk, bv, qT, kT, vT);
    attn_kernel<<<dim3(30, 64, 2), 64, 0, stream>>>(qT, kT, vT, PE, att);
    fc_kernel<<<120, 256, 0, stream>>>(att, fc_w, fc_b, Wout, bout, out);
}

// Round 4
// 62.586 us; speedup vs baseline: 2.0293x; 1.6601x over previous
//
#include <hip/hip_runtime.h>

// N=2, L=1024, C=256, H=64, E=16, CL=64, LOUT=960
// qT/kT: [n][h][l][e] fp32 ; vT: [n][h][l] fp32 ; attT: [n][h][l'] fp32

typedef __attribute__((ext_vector_type(8))) __bf16 bf16x8;
typedef __attribute__((ext_vector_type(8))) short short8;
typedef __attribute__((ext_vector_type(4))) float f32x4;

__device__ inline unsigned short bf16_rne(float x) {
    unsigned u = __builtin_bit_cast(unsigned, x);
    unsigned r = u + 0x7fffu + ((u >> 16) & 1u);
    return (unsigned short)(r >> 16);
}
__device__ inline float bf16_f(unsigned short h) {
    return __builtin_bit_cast(float, (unsigned)h << 16);
}

// ---------------------------------------------------------------------------
// Kernel 0: split X and W=[Wq;Wk;Wv] into bf16 hi/lo planes.
// ---------------------------------------------------------------------------
__global__ __launch_bounds__(256) void convert_split(
    const float* __restrict__ X,
    const float* __restrict__ Wq, const float* __restrict__ Wk, const float* __restrict__ Wv,
    unsigned short* __restrict__ XhG, unsigned short* __restrict__ XlG,
    unsigned short* __restrict__ WhG, unsigned short* __restrict__ WlG)
{
    const int g = blockIdx.x * 256 + threadIdx.x;
    const int NX = 131072;
    const int NW = 135168;
    if (g >= NX + NW) return;

    float4 v;
    unsigned short *dh, *dl;
    int off;
    if (g < NX) {
        off = g * 4;
        v = *reinterpret_cast<const float4*>(&X[off]);
        dh = XhG; dl = XlG;
    } else {
        off = (g - NX) * 4;
        const int row = off >> 8, col = off & 255;
        const float* s;
        if (row < 1024)      s = &Wq[row * 256 + col];
        else if (row < 2048) s = &Wk[(row - 1024) * 256 + col];
        else                 s = &Wv[(row - 2048) * 256 + col];
        v = *reinterpret_cast<const float4*>(s);
        dh = WhG; dl = WlG;
    }
    unsigned short h0 = bf16_rne(v.x), h1 = bf16_rne(v.y), h2 = bf16_rne(v.z), h3 = bf16_rne(v.w);
    unsigned short l0 = bf16_rne(v.x - bf16_f(h0));
    unsigned short l1 = bf16_rne(v.y - bf16_f(h1));
    unsigned short l2 = bf16_rne(v.z - bf16_f(h2));
    unsigned short l3 = bf16_rne(v.w - bf16_f(h3));
    ushort4 hv = make_ushort4(h0, h1, h2, h3);
    ushort4 lv = make_ushort4(l0, l1, l2, l3);
    *reinterpret_cast<ushort4*>(&dh[off]) = hv;
    *reinterpret_cast<ushort4*>(&dl[off]) = lv;
}

// ---------------------------------------------------------------------------
// Kernel 1: QKV projection via MFMA, bf16 split-3 (XhWh + XhWl + XlWh).
// ---------------------------------------------------------------------------
#define LDA 72

__global__ __launch_bounds__(256) void qkv_mfma(
    const unsigned short* __restrict__ XhG, const unsigned short* __restrict__ XlG,
    const unsigned short* __restrict__ WhG, const unsigned short* __restrict__ WlG,
    const float* __restrict__ bq, const float* __restrict__ bk, const float* __restrict__ bv,
    float* __restrict__ qT, float* __restrict__ kT, float* __restrict__ vT)
{
    __shared__ unsigned short A_lds[128 * LDA];
    __shared__ unsigned short B_lds[128 * LDA];
    __shared__ unsigned short C_lds[128 * LDA];

    const int tid = threadIdx.x;
    const int lane = tid & 63;
    const int wid = tid >> 6;
    const int wm = wid >> 1, wn = wid & 1;
    const int m0 = blockIdx.x * 128;
    const int o0 = blockIdx.y * 128;

    f32x4 acc[4][4];
    #pragma unroll
    for (int i = 0; i < 4; ++i)
        #pragma unroll
        for (int j = 0; j < 4; ++j)
            acc[i][j] = f32x4{0.f, 0.f, 0.f, 0.f};

    const short8 zero8 = {0, 0, 0, 0, 0, 0, 0, 0};

    for (int k0 = 0; k0 < 256; k0 += 64) {
        __syncthreads();
        #pragma unroll
        for (int i = tid; i < 1024; i += 256) {
            const int row = i >> 3, lc = (i & 7) * 8;
            *reinterpret_cast<short8*>(&A_lds[row * LDA + lc]) =
                *reinterpret_cast<const short8*>(&XhG[(m0 + row) * 256 + k0 + lc]);
            const int orow = o0 + row;
            short8 wh = zero8, wl = zero8;
            if (orow < 2112) {
                wh = *reinterpret_cast<const short8*>(&WhG[orow * 256 + k0 + lc]);
                wl = *reinterpret_cast<const short8*>(&WlG[orow * 256 + k0 + lc]);
            }
            *reinterpret_cast<short8*>(&B_lds[row * LDA + lc]) = wh;
            *reinterpret_cast<short8*>(&C_lds[row * LDA + lc]) = wl;
        }
        __syncthreads();
        #pragma unroll
        for (int kk = 0; kk < 64; kk += 32) {
            const int colb = kk + ((lane >> 4) << 3);
            bf16x8 aH[4], bH[4], bL[4];
            #pragma unroll
            for (int t = 0; t < 4; ++t) {
                const int ar = wm * 64 + t * 16 + (lane & 15);
                const int br = wn * 64 + t * 16 + (lane & 15);
                aH[t] = __builtin_bit_cast(bf16x8, *reinterpret_cast<const short8*>(&A_lds[ar * LDA + colb]));
                bH[t] = __builtin_bit_cast(bf16x8, *reinterpret_cast<const short8*>(&B_lds[br * LDA + colb]));
                bL[t] = __builtin_bit_cast(bf16x8, *reinterpret_cast<const short8*>(&C_lds[br * LDA + colb]));
            }
            #pragma unroll
            for (int mt = 0; mt < 4; ++mt)
                #pragma unroll
                for (int ot = 0; ot < 4; ++ot) {
                    acc[mt][ot] = __builtin_amdgcn_mfma_f32_16x16x32_bf16(aH[mt], bH[ot], acc[mt][ot], 0, 0, 0);
                    acc[mt][ot] = __builtin_amdgcn_mfma_f32_16x16x32_bf16(aH[mt], bL[ot], acc[mt][ot], 0, 0, 0);
                }
        }
        __syncthreads();
        #pragma unroll
        for (int i = tid; i < 1024; i += 256) {
            const int row = i >> 3, lc = (i & 7) * 8;
            *reinterpret_cast<short8*>(&C_lds[row * LDA + lc]) =
                *reinterpret_cast<const short8*>(&XlG[(m0 + row) * 256 + k0 + lc]);
        }
        __syncthreads();
        #pragma unroll
        for (int kk = 0; kk < 64; kk += 32) {
            const int colb = kk + ((lane >> 4) << 3);
            bf16x8 aL[4], bH[4];
            #pragma unroll
            for (int t = 0; t < 4; ++t) {
                const int ar = wm * 64 + t * 16 + (lane & 15);
                const int br = wn * 64 + t * 16 + (lane & 15);
                aL[t] = __builtin_bit_cast(bf16x8, *reinterpret_cast<const short8*>(&C_lds[ar * LDA + colb]));
                bH[t] = __builtin_bit_cast(bf16x8, *reinterpret_cast<const short8*>(&B_lds[br * LDA + colb]));
            }
            #pragma unroll
            for (int mt = 0; mt < 4; ++mt)
                #pragma unroll
                for (int ot = 0; ot < 4; ++ot)
                    acc[mt][ot] = __builtin_amdgcn_mfma_f32_16x16x32_bf16(aL[mt], bH[ot], acc[mt][ot], 0, 0, 0);
        }
    }

    const int drow = (lane >> 4) * 4;
    const int dcol = lane & 15;
    const int mode = (o0 < 1024) ? 0 : (o0 < 2048 ? 1 : 2);

    if (mode < 2) {
        float* __restrict__ T = mode ? kT : qT;
        const float* __restrict__ bias = mode ? bk : bq;
        const int ob = mode * 1024;
        #pragma unroll
        for (int ot = 0; ot < 4; ++ot) {
            const int o = o0 + wn * 64 + ot * 16 + dcol;
            const int h = (o >> 4) & 63;
            const int e = o & 15;
            const float bval = bias[o - ob];
            #pragma unroll
            for (int mt = 0; mt < 4; ++mt)
                #pragma unroll
                for (int r = 0; r < 4; ++r) {
                    const int m = m0 + wm * 64 + mt * 16 + drow + r;
                    const int n = m >> 10, l = m & 1023;
                    T[((n * 64 + h) * 1024 + l) * 16 + e] = acc[mt][ot][r] + bval;
                }
        }
    } else if (wn == 0) {
        #pragma unroll
        for (int ot = 0; ot < 4; ++ot) {
            const int hV = ot * 16 + dcol;
            const float bval = bv[hV];
            #pragma unroll
            for (int mt = 0; mt < 4; ++mt)
                #pragma unroll
                for (int r = 0; r < 4; ++r) {
                    const int m = m0 + wm * 64 + mt * 16 + drow + r;
                    const int n = m >> 10, l = m & 1023;
                    vT[(n * 64 + hV) * 1024 + l] = acc[mt][ot][r] + bval;
                }
        }
    }
}

// ---------------------------------------------------------------------------
// Kernel 2: sliding-window attention, lane = output position (NO cross-lane
// reduction). Block = 1 wave, handles (n,h,64 outputs). d-loop with online
// exp accumulation, fixed shift (exact softmax ratio, no max pass).
// k_lds row stride 20 floats (80B): b128 reads tile all 32 banks optimally.
// ---------------------------------------------------------------------------
__global__ __launch_bounds__(64) void attn_kernel(
    const float* __restrict__ qT, const float* __restrict__ kT,
    const float* __restrict__ vT, const float* __restrict__ PE,
    float* __restrict__ attT)
{
    __shared__ float k_lds[127 * 20];
    __shared__ float pe_lds[64 * 16];
    __shared__ float v_lds[128];

    const int lane = threadIdx.x;
    const int lt = blockIdx.x;   // 0..14
    const int h  = blockIdx.y;
    const int n  = blockIdx.z;
    const int l0 = lt * 64;

    const float4* kb4 = reinterpret_cast<const float4*>(kT + ((size_t)(n * 64 + h) * 1024 + l0) * 16);
    for (int u = lane; u < 508; u += 64) {          // 127 rows x 4 float4
        float4 g = kb4[u];
        const int row = u >> 2, f = u & 3;
        *reinterpret_cast<float4*>(&k_lds[row * 20 + f * 4]) = g;
    }
    for (int u = lane; u < 256; u += 64) {          // PE rows for this h
        const int d = u >> 2, f = u & 3;
        *reinterpret_cast<float4*>(&pe_lds[d * 16 + f * 4]) =
            *reinterpret_cast<const float4*>(&PE[(d * 64 + h) * 16 + f * 4]);
    }
    const float* vbase = vT + (size_t)(n * 64 + h) * 1024 + l0;
    for (int u = lane; u < 127; u += 64) v_lds[u] = vbase[u];

    float4 q0, q1, q2, q3;
    {
        const float4* qb = reinterpret_cast<const float4*>(
            qT + ((size_t)(n * 64 + h) * 1024 + l0 + 32 + lane) * 16);
        q0 = qb[0]; q1 = qb[1]; q2 = qb[2]; q3 = qb[3];
    }
    __syncthreads();

    float den = 0.f, pv = 0.f;
    #pragma unroll 2
    for (int d = 0; d < 64; ++d) {
        const float4* kr = reinterpret_cast<const float4*>(&k_lds[(lane + d) * 20]);
        const float4* pr = reinterpret_cast<const float4*>(&pe_lds[d * 16]);
        const float4 k0 = kr[0], k1 = kr[1], k2 = kr[2], k3 = kr[3];
        const float4 p0 = pr[0], p1 = pr[1], p2 = pr[2], p3 = pr[3];
        float s0 = (k0.x + p0.x) * q0.x + (k0.y + p0.y) * q0.y
                 + (k0.z + p0.z) * q0.z + (k0.w + p0.w) * q0.w;
        float s1 = (k1.x + p1.x) * q1.x + (k1.y + p1.y) * q1.y
                 + (k1.z + p1.z) * q1.z + (k1.w + p1.w) * q1.w;
        float s2 = (k2.x + p2.x) * q2.x + (k2.y + p2.y) * q2.y
                 + (k2.z + p2.z) * q2.z + (k2.w + p2.w) * q2.w;
        float s3 = (k3.x + p3.x) * q3.x + (k3.y + p3.y) * q3.y
                 + (k3.z + p3.z) * q3.z + (k3.w + p3.w) * q3.w;
        const float s = (s0 + s1) + (s2 + s3);
        const float p = __expf(s - 16.f);   // fixed shift: exact ratio, no max pass
        den += p;
        pv += p * v_lds[lane + d];
    }
    attT[(size_t)(n * 64 + h) * 960 + l0 + lane] = fmaxf(pv / den, 0.f);
}

// ---------------------------------------------------------------------------
// Kernel 3: 4x FC(64->64, ReLU) + head. 4 rows/block, thread = (row, output).
// ---------------------------------------------------------------------------
__global__ __launch_bounds__(256) void fc_kernel(
    const float* __restrict__ attT,
    const float* __restrict__ fc_w, const float* __restrict__ fc_b,
    const float* __restrict__ Wout, const float* __restrict__ bout,
    float* __restrict__ out)
{
    __shared__ float w_lds[64 * 68];
    __shared__ float wo_lds[3 * 64];
    __shared__ float bufA[4 * 68];
    __shared__ float bufB[4 * 68];

    const int tid = threadIdx.x;
    const int o = tid & 63;
    const int r = tid >> 6;            // 0..3 (wave id; uniform per wave)
    const int R0 = blockIdx.x * 4;     // rows R0..R0+3 of 1920
    const int n = R0 / 960;
    const int l0 = R0 - n * 960;

    for (int idx = tid; idx < 192; idx += 256) wo_lds[idx] = Wout[idx];
    {
        const int hh = tid >> 2, rr = tid & 3;
        bufA[rr * 68 + hh] = attT[(size_t)(n * 64 + hh) * 960 + l0 + rr];
    }

    float* cur = bufA;
    float* nxt = bufB;

    for (int layer = 0; layer < 4; ++layer) {
        __syncthreads();   // prev nxt writes visible; w_lds free
        const float4* wsrc = reinterpret_cast<const float4*>(fc_w + layer * 4096);
        for (int u = tid; u < 1024; u += 256) {
            const int oo = u >> 4, f = u & 15;
            *reinterpret_cast<float4*>(&w_lds[oo * 68 + f * 4]) = wsrc[u];
        }
        __syncthreads();
        float acc = fc_b[layer * 64 + o];
        const float4* wr = reinterpret_cast<const float4*>(&w_lds[o * 68]);
        const float4* cr = reinterpret_cast<const float4*>(&cur[r * 68]);
        #pragma unroll
        for (int t = 0; t < 16; ++t) {
            const float4 c = cr[t], w = wr[t];
            acc += c.x * w.x + c.y * w.y + c.z * w.z + c.w * w.w;
        }
        nxt[r * 68 + o] = fmaxf(acc, 0.f);
        float* tmp = cur; cur = nxt; nxt = tmp;
    }
    __syncthreads();

    if (o < 3) {
        float acc = bout[o];
        #pragma unroll
        for (int hh = 0; hh < 64; ++hh)
            acc += cur[r * 68 + hh] * wo_lds[o * 64 + hh];
        out[(R0 + r) * 3 + o] = acc;
    }
}

// ---------------------------------------------------------------------------
extern "C" void kernel_launch(void* const* d_in, const int* in_sizes, int n_in,
                              void* d_out, int out_size, void* d_ws, size_t ws_size,
                              hipStream_t stream) {
    const float* x    = (const float*)d_in[0];
    const float* Wq   = (const float*)d_in[1];
    const float* bq   = (const float*)d_in[2];
    const float* Wk   = (const float*)d_in[3];
    const float* bk   = (const float*)d_in[4];
    const float* Wv   = (const float*)d_in[5];
    const float* bv   = (const float*)d_in[6];
    const float* PE   = (const float*)d_in[7];
    const float* fc_w = (const float*)d_in[8];
    const float* fc_b = (const float*)d_in[9];
    const float* Wout = (const float*)d_in[10];
    const float* bout = (const float*)d_in[11];
    float* out = (float*)d_out;

    float* ws = (float*)d_ws;
    float* qT   = ws;                      // 2,097,152 f
    float* kT   = qT + 2097152;            // 2,097,152 f
    float* vT   = kT + 2097152;            // 131,072 f
    float* attT = vT + 131072;             // 122,880 f  [n][h][960]
    unsigned short* XhG = (unsigned short*)(attT + 122880);
    unsigned short* XlG = XhG + 524288;
    unsigned short* WhG = XlG + 524288;
    unsigned short* WlG = WhG + 540672;

    convert_split<<<1040, 256, 0, stream>>>(x, Wq, Wk, Wv, XhG, XlG, WhG, WlG);
    qkv_mfma<<<dim3(16, 17), 256, 0, stream>>>(XhG, XlG, WhG, WlG, bq, bk, bv, qT, kT, vT);
    attn_kernel<<<dim3(15, 64, 2), 64, 0, stream>>>(qT, kT, vT, PE, attT);
    fc_kernel<<<480, 256, 0, stream>>>(attT, fc_w, fc_b, Wout, bout, out);
}

// Round 5
// 52.998 us; speedup vs baseline: 2.3964x; 1.1809x over previous
//
#include <hip/hip_runtime.h>

// N=2, L=1024, C=256, H=64, E=16, CL=64, LOUT=960
// qT/kT: [n][h][l][e] fp32 ; vT: [n][h][l] fp32 ; attT: [n][h][l'] fp32

typedef __attribute__((ext_vector_type(8))) __bf16 bf16x8;
typedef __attribute__((ext_vector_type(8))) short short8;
typedef __attribute__((ext_vector_type(4))) float f32x4;

__device__ inline unsigned short bf16_rne(float x) {
    unsigned u = __builtin_bit_cast(unsigned, x);
    unsigned r = u + 0x7fffu + ((u >> 16) & 1u);
    return (unsigned short)(r >> 16);
}
__device__ inline float bf16_f(unsigned short h) {
    return __builtin_bit_cast(float, (unsigned)h << 16);
}

// ---------------------------------------------------------------------------
// Kernel 0: split X and W=[Wq;Wk;Wv] into bf16 hi/lo planes.
// ---------------------------------------------------------------------------
__global__ __launch_bounds__(256) void convert_split(
    const float* __restrict__ X,
    const float* __restrict__ Wq, const float* __restrict__ Wk, const float* __restrict__ Wv,
    unsigned short* __restrict__ XhG, unsigned short* __restrict__ XlG,
    unsigned short* __restrict__ WhG, unsigned short* __restrict__ WlG)
{
    const int g = blockIdx.x * 256 + threadIdx.x;
    const int NX = 131072;
    const int NW = 135168;
    if (g >= NX + NW) return;

    float4 v;
    unsigned short *dh, *dl;
    int off;
    if (g < NX) {
        off = g * 4;
        v = *reinterpret_cast<const float4*>(&X[off]);
        dh = XhG; dl = XlG;
    } else {
        off = (g - NX) * 4;
        const int row = off >> 8, col = off & 255;
        const float* s;
        if (row < 1024)      s = &Wq[row * 256 + col];
        else if (row < 2048) s = &Wk[(row - 1024) * 256 + col];
        else                 s = &Wv[(row - 2048) * 256 + col];
        v = *reinterpret_cast<const float4*>(s);
        dh = WhG; dl = WlG;
    }
    unsigned short h0 = bf16_rne(v.x), h1 = bf16_rne(v.y), h2 = bf16_rne(v.z), h3 = bf16_rne(v.w);
    unsigned short l0 = bf16_rne(v.x - bf16_f(h0));
    unsigned short l1 = bf16_rne(v.y - bf16_f(h1));
    unsigned short l2 = bf16_rne(v.z - bf16_f(h2));
    unsigned short l3 = bf16_rne(v.w - bf16_f(h3));
    ushort4 hv = make_ushort4(h0, h1, h2, h3);
    ushort4 lv = make_ushort4(l0, l1, l2, l3);
    *reinterpret_cast<ushort4*>(&dh[off]) = hv;
    *reinterpret_cast<ushort4*>(&dl[off]) = lv;
}

// ---------------------------------------------------------------------------
// Kernel 1 (v2): QKV projection via MFMA, bf16 split-3 (XhWh + XhWl + XlWh).
// 512 thr (8 waves, 2m x 4n, wave tile 64x32). Tile 128x128, k-step 64.
// LDS: 4 tiles [Xh|Xl|Wh|Wl] x 128row x 64 bf16 = 65536 B exactly, no pad.
// Bank conflicts handled by XOR swizzle (16B slot s stored at s^(row&7)),
// realized as pre-swizzled GLOBAL source + linear global_load_lds dest
// (rule 21: both-sides-or-neither), swizzled ds_read on the read side.
// Staging = global_load_lds width 16 (1 instr per 1KB chunk per wave).
// Grid (16,17): o0=2048 block computes V (cols 2048..2111 stored; 2112+
// read in-workspace garbage, never stored).
// ---------------------------------------------------------------------------
__device__ __forceinline__ bf16x8 ldsfrag(const unsigned short* lds, int t, int row, int so) {
    return __builtin_bit_cast(bf16x8, *reinterpret_cast<const short8*>(
        lds + t * 8192 + row * 64 + (((so ^ (row & 7)) & 7) << 3)));
}

__global__ __launch_bounds__(512, 4) void qkv_mfma(
    const unsigned short* __restrict__ XhG, const unsigned short* __restrict__ XlG,
    const unsigned short* __restrict__ WhG, const unsigned short* __restrict__ WlG,
    const float* __restrict__ bq, const float* __restrict__ bk, const float* __restrict__ bv,
    float* __restrict__ qT, float* __restrict__ kT, float* __restrict__ vT)
{
    __shared__ unsigned short lds[4 * 128 * 64];   // 64 KB

    const int tid  = threadIdx.x;
    const int lane = tid & 63;
    const int wid  = tid >> 6;          // 0..7
    const int wm   = wid >> 2;          // 0..1 -> m half (64 rows)
    const int wn   = wid & 3;           // 0..3 -> n quarter (32 cols)
    const int m0 = blockIdx.x * 128;
    const int o0 = blockIdx.y * 128;

    f32x4 acc[4][2];
    #pragma unroll
    for (int i = 0; i < 4; ++i)
        #pragma unroll
        for (int j = 0; j < 2; ++j)
            acc[i][j] = f32x4{0.f, 0.f, 0.f, 0.f};

    // per-lane swizzled-source geometry for staging
    const int r8 = lane >> 3;           // row within 8-row chunk
    const int ss = (lane & 7) ^ r8;     // swizzled source slot (8 bf16 each)

    for (int k0 = 0; k0 < 256; k0 += 64) {
        // ---- stage all 4 tiles via global_load_lds (8 chunks per wave)
        #pragma unroll
        for (int j = 0; j < 8; ++j) {
            const int c   = (wid << 3) | j;   // chunk 0..63 (wave-uniform)
            const int t   = c >> 4;           // tile 0..3 (wave-uniform)
            const int rg  = c & 15;           // row group (8 rows)
            const int row = (rg << 3) + r8;
            const unsigned short* gsrc;
            if (t == 0)      gsrc = &XhG[(m0 + row) * 256 + k0 + (ss << 3)];
            else if (t == 1) gsrc = &XlG[(m0 + row) * 256 + k0 + (ss << 3)];
            else if (t == 2) gsrc = &WhG[(o0 + row) * 256 + k0 + (ss << 3)];
            else             gsrc = &WlG[(o0 + row) * 256 + k0 + (ss << 3)];
            char* lbase = (char*)lds + (c << 10);   // uniform; HW adds lane*16
            __builtin_amdgcn_global_load_lds(
                (const __attribute__((address_space(1))) void*)gsrc,
                (__attribute__((address_space(3))) void*)lbase, 16, 0, 0);
        }
        __syncthreads();   // drains vmcnt before barrier

        // ---- compute: 48 MFMA per k0 per wave
        #pragma unroll
        for (int kk = 0; kk < 64; kk += 32) {
            const int so = (kk >> 3) + (lane >> 4);   // 16B slot index 0..7
            bf16x8 aH[4], aL[4], bH[2], bL[2];
            #pragma unroll
            for (int mt = 0; mt < 4; ++mt) {
                const int ar = wm * 64 + mt * 16 + (lane & 15);
                aH[mt] = ldsfrag(lds, 0, ar, so);
                aL[mt] = ldsfrag(lds, 1, ar, so);
            }
            #pragma unroll
            for (int ot = 0; ot < 2; ++ot) {
                const int br = wn * 32 + ot * 16 + (lane & 15);
                bH[ot] = ldsfrag(lds, 2, br, so);
                bL[ot] = ldsfrag(lds, 3, br, so);
            }
            #pragma unroll
            for (int mt = 0; mt < 4; ++mt)
                #pragma unroll
                for (int ot = 0; ot < 2; ++ot) {
                    acc[mt][ot] = __builtin_amdgcn_mfma_f32_16x16x32_bf16(aH[mt], bH[ot], acc[mt][ot], 0, 0, 0);
                    acc[mt][ot] = __builtin_amdgcn_mfma_f32_16x16x32_bf16(aH[mt], bL[ot], acc[mt][ot], 0, 0, 0);
                    acc[mt][ot] = __builtin_amdgcn_mfma_f32_16x16x32_bf16(aL[mt], bH[ot], acc[mt][ot], 0, 0, 0);
                }
        }
        __syncthreads();   // protect LDS before next stage
    }

    // ---- epilogue: bias + transposed scatter
    const int drow = (lane >> 4) * 4;
    const int dcol = lane & 15;
    const int mode = (o0 < 1024) ? 0 : (o0 < 2048 ? 1 : 2);

    if (mode < 2) {
        float* __restrict__ T = mode ? kT : qT;
        const float* __restrict__ bias = mode ? bk : bq;
        const int ob = mode * 1024;
        #pragma unroll
        for (int ot = 0; ot < 2; ++ot) {
            const int o = o0 + wn * 32 + ot * 16 + dcol;
            const int h = (o >> 4) & 63;
            const int e = o & 15;
            const float bval = bias[o - ob];
            #pragma unroll
            for (int mt = 0; mt < 4; ++mt)
                #pragma unroll
                for (int r = 0; r < 4; ++r) {
                    const int m = m0 + wm * 64 + mt * 16 + drow + r;
                    const int n = m >> 10, l = m & 1023;
                    T[((n * 64 + h) * 1024 + l) * 16 + e] = acc[mt][ot][r] + bval;
                }
        }
    } else if (wn < 2) {   // V: cols 2048..2111 only
        #pragma unroll
        for (int ot = 0; ot < 2; ++ot) {
            const int hV = wn * 32 + ot * 16 + dcol;   // 0..63
            const float bval = bv[hV];
            #pragma unroll
            for (int mt = 0; mt < 4; ++mt)
                #pragma unroll
                for (int r = 0; r < 4; ++r) {
                    const int m = m0 + wm * 64 + mt * 16 + drow + r;
                    const int n = m >> 10, l = m & 1023;
                    vT[(n * 64 + hV) * 1024 + l] = acc[mt][ot][r] + bval;
                }
        }
    }
}

// ---------------------------------------------------------------------------
// Kernel 2: sliding-window attention, lane = output position (NO cross-lane
// reduction). Block = 1 wave, handles (n,h,64 outputs). d-loop with online
// exp accumulation, fixed shift (exact softmax ratio, no max pass).
// ---------------------------------------------------------------------------
__global__ __launch_bounds__(64) void attn_kernel(
    const float* __restrict__ qT, const float* __restrict__ kT,
    const float* __restrict__ vT, const float* __restrict__ PE,
    float* __restrict__ attT)
{
    __shared__ float k_lds[127 * 20];
    __shared__ float pe_lds[64 * 16];
    __shared__ float v_lds[128];

    const int lane = threadIdx.x;
    const int lt = blockIdx.x;   // 0..14
    const int h  = blockIdx.y;
    const int n  = blockIdx.z;
    const int l0 = lt * 64;

    const float4* kb4 = reinterpret_cast<const float4*>(kT + ((size_t)(n * 64 + h) * 1024 + l0) * 16);
    for (int u = lane; u < 508; u += 64) {
        float4 g = kb4[u];
        const int row = u >> 2, f = u & 3;
        *reinterpret_cast<float4*>(&k_lds[row * 20 + f * 4]) = g;
    }
    for (int u = lane; u < 256; u += 64) {
        const int d = u >> 2, f = u & 3;
        *reinterpret_cast<float4*>(&pe_lds[d * 16 + f * 4]) =
            *reinterpret_cast<const float4*>(&PE[(d * 64 + h) * 16 + f * 4]);
    }
    const float* vbase = vT + (size_t)(n * 64 + h) * 1024 + l0;
    for (int u = lane; u < 127; u += 64) v_lds[u] = vbase[u];

    float4 q0, q1, q2, q3;
    {
        const float4* qb = reinterpret_cast<const float4*>(
            qT + ((size_t)(n * 64 + h) * 1024 + l0 + 32 + lane) * 16);
        q0 = qb[0]; q1 = qb[1]; q2 = qb[2]; q3 = qb[3];
    }
    __syncthreads();

    float den = 0.f, pv = 0.f;
    #pragma unroll 2
    for (int d = 0; d < 64; ++d) {
        const float4* kr = reinterpret_cast<const float4*>(&k_lds[(lane + d) * 20]);
        const float4* pr = reinterpret_cast<const float4*>(&pe_lds[d * 16]);
        const float4 k0 = kr[0], k1 = kr[1], k2 = kr[2], k3 = kr[3];
        const float4 p0 = pr[0], p1 = pr[1], p2 = pr[2], p3 = pr[3];
        float s0 = (k0.x + p0.x) * q0.x + (k0.y + p0.y) * q0.y
                 + (k0.z + p0.z) * q0.z + (k0.w + p0.w) * q0.w;
        float s1 = (k1.x + p1.x) * q1.x + (k1.y + p1.y) * q1.y
                 + (k1.z + p1.z) * q1.z + (k1.w + p1.w) * q1.w;
        float s2 = (k2.x + p2.x) * q2.x + (k2.y + p2.y) * q2.y
                 + (k2.z + p2.z) * q2.z + (k2.w + p2.w) * q2.w;
        float s3 = (k3.x + p3.x) * q3.x + (k3.y + p3.y) * q3.y
                 + (k3.z + p3.z) * q3.z + (k3.w + p3.w) * q3.w;
        const float s = (s0 + s1) + (s2 + s3);
        const float p = __expf(s - 16.f);
        den += p;
        pv += p * v_lds[lane + d];
    }
    attT[(size_t)(n * 64 + h) * 960 + l0 + lane] = fmaxf(pv / den, 0.f);
}

// ---------------------------------------------------------------------------
// Kernel 3: 4x FC(64->64, ReLU) + head. 4 rows/block, thread = (row, output).
// ---------------------------------------------------------------------------
__global__ __launch_bounds__(256) void fc_kernel(
    const float* __restrict__ attT,
    const float* __restrict__ fc_w, const float* __restrict__ fc_b,
    const float* __restrict__ Wout, const float* __restrict__ bout,
    float* __restrict__ out)
{
    __shared__ float w_lds[64 * 68];
    __shared__ float wo_lds[3 * 64];
    __shared__ float bufA[4 * 68];
    __shared__ float bufB[4 * 68];

    const int tid = threadIdx.x;
    const int o = tid & 63;
    const int r = tid >> 6;
    const int R0 = blockIdx.x * 4;
    const int n = R0 / 960;
    const int l0 = R0 - n * 960;

    for (int idx = tid; idx < 192; idx += 256) wo_lds[idx] = Wout[idx];
    {
        const int hh = tid >> 2, rr = tid & 3;
        bufA[rr * 68 + hh] = attT[(size_t)(n * 64 + hh) * 960 + l0 + rr];
    }

    float* cur = bufA;
    float* nxt = bufB;

    for (int layer = 0; layer < 4; ++layer) {
        __syncthreads();
        const float4* wsrc = reinterpret_cast<const float4*>(fc_w + layer * 4096);
        for (int u = tid; u < 1024; u += 256) {
            const int oo = u >> 4, f = u & 15;
            *reinterpret_cast<float4*>(&w_lds[oo * 68 + f * 4]) = wsrc[u];
        }
        __syncthreads();
        float acc = fc_b[layer * 64 + o];
        const float4* wr = reinterpret_cast<const float4*>(&w_lds[o * 68]);
        const float4* cr = reinterpret_cast<const float4*>(&cur[r * 68]);
        #pragma unroll
        for (int t = 0; t < 16; ++t) {
            const float4 c = cr[t], w = wr[t];
            acc += c.x * w.x + c.y * w.y + c.z * w.z + c.w * w.w;
        }
        nxt[r * 68 + o] = fmaxf(acc, 0.f);
        float* tmp = cur; cur = nxt; nxt = tmp;
    }
    __syncthreads();

    if (o < 3) {
        float acc = bout[o];
        #pragma unroll
        for (int hh = 0; hh < 64; ++hh)
            acc += cur[r * 68 + hh] * wo_lds[o * 64 + hh];
        out[(R0 + r) * 3 + o] = acc;
    }
}

// ---------------------------------------------------------------------------
extern "C" void kernel_launch(void* const* d_in, const int* in_sizes, int n_in,
                              void* d_out, int out_size, void* d_ws, size_t ws_size,
                              hipStream_t stream) {
    const float* x    = (const float*)d_in[0];
    const float* Wq   = (const float*)d_in[1];
    const float* bq   = (const float*)d_in[2];
    const float* Wk   = (const float*)d_in[3];
    const float* bk   = (const float*)d_in[4];
    const float* Wv   = (const float*)d_in[5];
    const float* bv   = (const float*)d_in[6];
    const float* PE   = (const float*)d_in[7];
    const float* fc_w = (const float*)d_in[8];
    const float* fc_b = (const float*)d_in[9];
    const float* Wout = (const float*)d_in[10];
    const float* bout = (const float*)d_in[11];
    float* out = (float*)d_out;

    float* ws = (float*)d_ws;
    float* qT   = ws;                      // 2,097,152 f
    float* kT   = qT + 2097152;            // 2,097,152 f
    float* vT   = kT + 2097152;            // 131,072 f
    float* attT = vT + 131072;             // 122,880 f  [n][h][960]
    unsigned short* XhG = (unsigned short*)(attT + 122880);
    unsigned short* XlG = XhG + 524288;
    unsigned short* WhG = XlG + 524288;
    unsigned short* WlG = WhG + 540672;

    convert_split<<<1040, 256, 0, stream>>>(x, Wq, Wk, Wv, XhG, XlG, WhG, WlG);
    qkv_mfma<<<dim3(16, 17), 512, 0, stream>>>(XhG, XlG, WhG, WlG, bq, bk, bv, qT, kT, vT);
    attn_kernel<<<dim3(15, 64, 2), 64, 0, stream>>>(qT, kT, vT, PE, attT);
    fc_kernel<<<480, 256, 0, stream>>>(attT, fc_w, fc_b, Wout, bout, out);
}